// Round 8
// baseline (283.461 us; speedup 1.0000x reference)
//
#include <hip/hip_runtime.h>
#include <hip/hip_bf16.h>

#define Mm 8
#define Nn 512
#define NEe 409
#define NIi 103
#define Bb 512
#define Dd 243
#define Tt 16
#define SPB 96         // bit-packed spike row bytes: e-bits[0,64) | i-bits[64,80) | pad[80,96)
#define SPTICK (Mm * Bb * SPB)   // 393,216 B: one spike buffer per tick (16 total -> no WAR)
#define WCROW 1152     // packed weight row bytes (i8): inter(512) | E-rec(512) | I-rec(128, data at [1049,1152))
#define DEC_I 0.33333334f  // (float)(1.0 - 1.0/1.5)
#define NBLK 256
#define FLAGSTRIDE 16  // one flag per 64B cache line
#define SPINMAX 1000000L
#define ABROW 176      // LDS A-bit row stride (mult 16; word-stride 44 -> 2-way-free banks)

typedef int v4i __attribute__((ext_vector_type(4)));
union BV { signed char b[16]; v4i v; };

__device__ __forceinline__ float quantf(float w) {
    // fake_quant forward == clip(round-half-even(w), -8, 7)  (step = 1.0)
    float q = rintf(w);
    return fminf(fmaxf(q, -8.0f), 7.0f);
}

// nibble -> 4 bytes of 0/1: (nib * 0x204081) & 0x01010101 places bit j at byte j.
__device__ __forceinline__ v4i unpack16(unsigned int dl, unsigned int dh, bool qhi, int qsh) {
    unsigned int d = qhi ? dh : dl;
    v4i r;
    r[0] = (int)((((d >> qsh) & 0xFu) * 0x00204081u) & 0x01010101u);
    r[1] = (int)((((d >> (qsh + 4)) & 0xFu) * 0x00204081u) & 0x01010101u);
    r[2] = (int)((((d >> (qsh + 8)) & 0xFu) * 0x00204081u) & 0x01010101u);
    r[3] = (int)((((d >> (qsh + 12)) & 0xFu) * 0x00204081u) & 0x01010101u);
    return r;
}

// ---------------- persistent 16-tick LIF, fused ext-GEMM + fused weight pack --------
// 256 blocks x 512 thr, tile 64b x 128n. r4 (best-verified, 198.7us) structure with
// the k_pack dispatch ELIMINATED: each block quantizes+packs its own 128 B-rows
// directly into sB during the prologue (same K layout: [0,512) inter from prev mesh
// [valid k<409], [512,1024) E-rec [valid jj<409], [1024,1152) I-rec rebased to
// jj=k-1049; same gs granule XOR-swizzle; same quantf rounding). Wc and its global
// round trip are gone. Sp+flags zeroing moved to one hipMemsetAsync (launch-
// invariance: r0 tripwire lesson). Tick protocol is r4 verbatim: block-wide 8-flag
// RAW wait {pm,m}x4nt', block-wide staging, 3 barriers/tick, ballot publish,
// 16 per-tick spike buffers (no WAR). LDS 155 KB, 1 block/CU.
__global__ void __launch_bounds__(512, 2)
k_ticks(const float* __restrict__ Wint, const float* __restrict__ WEE,
        const float* __restrict__ WEI, const float* __restrict__ WIE,
        const float* __restrict__ WII,
        unsigned char* __restrict__ Sp,
        const float* __restrict__ x,
        const float* __restrict__ Win,
        const float* __restrict__ bin,
        float* __restrict__ out,
        int* __restrict__ flags) {
    __shared__ __align__(16) signed char sB[128 * WCROW];     // 144 KB resident weights
    __shared__ __align__(16) unsigned char sAb[64 * ABROW];   // 11 KB per-tick spike bits

    const int wg = blockIdx.x;           // 256: m(8) x bt(8) x nt(4)
    const int m  = wg & 7;               // mesh -> XCD affinity heuristic
    const int bt = (wg >> 3) & 7;
    const int nt = wg >> 6;              // 0..3
    const int b0 = bt * 64;
    const int n0 = nt * 128;
    const int pm = (m + 7) & 7;

    const int tid  = threadIdx.x;        // 0..511
    const int w    = tid >> 6;           // 0..7
    const int lane = tid & 63;
    const int bh   = w & 1;              // 32-row half of b-tile
    const int nh   = w >> 1;             // 0..3: 32-col slice of n-tile
    const int quad = lane >> 4;
    const int li   = lane & 15;

    // RAW wait-set for tid<8: mesh {pm,m}[tid>=4], nt'=tid&3, same bt
    int waitIdx = 0;
    if (tid < 8) {
        int mm = (tid < 4) ? pm : m;
        waitIdx = (((tid & 3) << 6) | (bt << 3) | mm) * FLAGSTRIDE;
    }

    float decs[2]; int nels[2];
    int styp[2], soff[2];                // publish: 0/1 = plain halfword @soff, 2 = mixed
#pragma unroll
    for (int tn = 0; tn < 2; ++tn) {
        int n = n0 + nh * 32 + tn * 16 + li;
        nels[tn] = n;
        decs[tn] = (n < NEe) ? 0.5f : DEC_I;
        int nb = n0 + nh * 32 + tn * 16;           // wave-uniform 16-group base
        if (nb < 400)      { styp[tn] = 0; soff[tn] = nb >> 3; }
        else if (nb == 400){ styp[tn] = 2; soff[tn] = 50; }
        else               { styp[tn] = 1; soff[tn] = 64 + ((nb - 384) >> 3); }
    }
    const int bbase = b0 + bh * 32;

    // ---- fused ext phase: two 64x64 sub-tiles, r8-verified chunk-64 logic verbatim --
    // group g = tid>>8 handles n columns [n0+g*64, +64); LDS xs/wsm aliased inside sB.
    {
        const int g   = tid >> 8;
        const int t8  = tid & 255;
        const int n0e = n0 + g * 64;
        float* xs  = (float*)sB + g * (2 * 64 * 68);
        float* wsm = xs + 64 * 68;
        const int etb4 = (t8 & 15) * 4;
        const int etn4 = (t8 >> 4) * 4;
        const int sr = t8 >> 2;
        const int sc = (t8 & 3) * 16;
        float c[4][4];
#pragma unroll
        for (int i = 0; i < 4; ++i)
#pragma unroll
            for (int j = 0; j < 4; ++j) c[i][j] = 0.0f;

        for (int d0 = 0; d0 < Dd; d0 += 64) {
#pragma unroll
            for (int j = 0; j < 16; ++j) {
                int d = d0 + sc + j;
                float xv = 0.0f, wv = 0.0f;
                if (d < Dd) {
                    xv = x[(b0 + sr) * Dd + d];
                    wv = quantf(Win[((m * Nn) + n0e + sr) * Dd + d]);
                }
                xs[(sc + j) * 68 + sr] = xv;
                wsm[(sc + j) * 68 + sr] = wv;
            }
            __syncthreads();
            const int dmax = min(64, Dd - d0);
            for (int d = 0; d < dmax; ++d) {
                float4 av = *(const float4*)&xs[d * 68 + etb4];
                float4 wv = *(const float4*)&wsm[d * 68 + etn4];
                float a[4] = {av.x, av.y, av.z, av.w};
                float wq[4] = {wv.x, wv.y, wv.z, wv.w};
#pragma unroll
                for (int i = 0; i < 4; ++i)
#pragma unroll
                    for (int j = 0; j < 4; ++j)
                        c[i][j] = fmaf(a[i], wq[j], c[i][j]);
            }
            __syncthreads();
        }
        // redistribute: extbuf[64][128] fp32 (32KB) aliases start of sB (safe: all
        // xs/wsm reads drained by the loop-final barrier)
        float* extbuf = (float*)sB;
#pragma unroll
        for (int i = 0; i < 4; ++i)
#pragma unroll
            for (int j = 0; j < 4; ++j)
                extbuf[(etb4 + i) * 128 + g * 64 + etn4 + j] =
                    __fadd_rn(c[i][j], bin[m * Nn + n0e + etn4 + j]);
        __syncthreads();
    }

    // per-thread persistent ext values for all 16 ticks (bitwise = k_ext output)
    float extr[2][2][4];
#pragma unroll
    for (int tb = 0; tb < 2; ++tb)
#pragma unroll
        for (int tn = 0; tn < 2; ++tn)
#pragma unroll
            for (int r = 0; r < 4; ++r)
                extr[tb][tn][r] = ((const float*)sB)[(bh * 32 + tb * 16 + quad * 4 + r) * 128
                                                     + (nels[tn] - n0)];
    __syncthreads();   // all extr reads drained before pack overwrites sB

    // ---- fused weight pack: quantize fp32 sources straight into sB ----------------
    // 9216 granules of 16 bytes; granule (row,gg) covers K [gg*16, gg*16+16) of
    // global row n = n0+row, stored at gs (XOR-swizzle within 256B spans).
#pragma unroll
    for (int j = 0; j < 18; ++j) {
        int task = tid + j * 512;                 // exactly 9216 = 512*18
        int row = task / 72, gg = task % 72;
        int n = n0 + row;
        BV pk;
#pragma unroll
        for (int e = 0; e < 16; ++e) {
            int k = gg * 16 + e;
            float wv = 0.0f;
            if (k < 512) {
                if (k < NEe) wv = Wint[((pm * Nn) + n) * NEe + k];
            } else if (k < 1024) {
                int jj = k - 512;
                if (jj < NEe) wv = (n < NEe) ? WEE[((m * NEe) + n) * NEe + jj]
                                             : WEI[((m * NIi) + (n - NEe)) * NEe + jj];
            } else {
                int jj = k - 1049;                 // rebased I segment
                if (jj >= 0 && jj < NIi) wv = (n < NEe) ? WIE[((m * NEe) + n) * NIi + jj]
                                             : WII[((m * NIi) + (n - NEe)) * NIi + jj];
            }
            pk.b[e] = (signed char)(int)quantf(wv);
        }
        int gs = (gg < 64) ? ((gg & 48) | ((gg ^ row) & 15))
                           : (64 + ((gg ^ row) & 7));
        *(v4i*)&sB[row * WCROW + gs * 16] = pk.v;
    }
    // never-written sAb slots (e-bits [416,512) both halves) zeroed once:
    // slots 13,14,15 (prev-e) and 29,30,31 (own-e) per row.
    if (tid < 384) {
        int row = tid / 6, z = tid - (tid / 6) * 6;
        int s = (z < 3) ? (13 + z) : (26 + z);     // 13,14,15 / 29,30,31
        *(unsigned*)&sAb[row * ABROW + s * 4] = 0u;
    }
    __syncthreads();

    float vmem[2][2][4];
    int cnt[2][2];
#pragma unroll
    for (int tb = 0; tb < 2; ++tb)
#pragma unroll
        for (int tn = 0; tn < 2; ++tn) {
            cnt[tb][tn] = 0;
#pragma unroll
            for (int r = 0; r < 4; ++r) vmem[tb][tn][r] = 0.0f;
        }

    const bool qhi = (quad >= 2);
    const int qsh = (quad & 1) << 4;
    const int r0base = (bh * 32 + li) * ABROW;
    const int r1base = (bh * 32 + 16 + li) * ABROW;

    for (int t = 0; t < Tt; ++t) {
        float c[2][2][4];

        if (t == 0) {
            // spikes all zero: c = ((ext + 0) + 0) + 0, exact fadd chain as GEMM path
#pragma unroll
            for (int tb = 0; tb < 2; ++tb)
#pragma unroll
                for (int tn = 0; tn < 2; ++tn)
#pragma unroll
                    for (int r = 0; r < 4; ++r)
                        c[tb][tn][r] = __fadd_rn(__fadd_rn(__fadd_rn(extr[tb][tn][r], 0.0f), 0.0f), 0.0f);
        } else {
            // RAW wait: 8 flags {pm,m} x nt' at level t, then bulk-stage with full MLP
            if (tid < 8) {
                long spin = 0;
                while (__hip_atomic_load(&flags[waitIdx],
                                         __ATOMIC_RELAXED, __HIP_MEMORY_SCOPE_AGENT) < t) {
                    __builtin_amdgcn_s_sleep(2);
                    if (++spin > SPINMAX) break;   // bail: wrong answer beats a hang
                }
            }
            __syncthreads();

            // ---- stage A-bits: LDS row = [prev-e 64B | own-e 64B | own-i 16B | pad] ----
            const unsigned char* SR = Sp + (size_t)(t - 1) * SPTICK;
            const unsigned char* PrevRow = SR + (size_t)(pm * Bb + b0) * SPB;
            const unsigned char* OwnRow  = SR + (size_t)(m  * Bb + b0) * SPB;
#pragma unroll
            for (int j = 0; j < 3; ++j) {
                int task = tid + j * 512;              // 1152 u64 tasks
                if (task < 1152) {
                    int row = task / 18, s = task % 18;
                    const unsigned char* src;
                    int dstoff;
                    if (s < 8)       { src = PrevRow + (size_t)row * SPB + s * 8;            dstoff = s * 8; }
                    else if (s < 16) { src = OwnRow  + (size_t)row * SPB + (s - 8) * 8;      dstoff = s * 8; }
                    else             { src = OwnRow  + (size_t)row * SPB + 64 + (s - 16) * 8; dstoff = 128 + (s - 16) * 8; }
                    unsigned long long vb = __hip_atomic_load((const unsigned long long*)src,
                                               __ATOMIC_RELAXED, __HIP_MEMORY_SCOPE_AGENT);
                    *(unsigned long long*)&sAb[row * ABROW + dstoff] = vb;
                }
            }
            __syncthreads();

            v4i acc[2][2];
#pragma unroll
            for (int tb = 0; tb < 2; ++tb)
#pragma unroll
                for (int tn = 0; tn < 2; ++tn) acc[tb][tn] = (v4i){0, 0, 0, 0};

            // ---- 4 full 256-wide K-chunks, no barriers (B resident, A in regs) ----
#pragma unroll
            for (int ch = 0; ch < 4; ++ch) {
                const int cb = ch << 8;
                v4i a0lo = *(const v4i*)&sAb[r0base + (cb >> 3)];
                v4i a0hi = *(const v4i*)&sAb[r0base + (cb >> 3) + 16];
                v4i a1lo = *(const v4i*)&sAb[r1base + (cb >> 3)];
                v4i a1hi = *(const v4i*)&sAb[r1base + (cb >> 3) + 16];
#pragma unroll
                for (int ks = 0; ks < 256; ks += 64) {
                    v4i s0 = (ks < 128) ? a0lo : a0hi;
                    v4i s1 = (ks < 128) ? a1lo : a1hi;
                    const int D0 = ((ks >> 6) & 1) ? 2 : 0;
                    v4i af0 = unpack16((unsigned int)s0[D0], (unsigned int)s0[D0 + 1], qhi, qsh);
                    v4i af1 = unpack16((unsigned int)s1[D0], (unsigned int)s1[D0 + 1], qhi, qsh);
                    const int gs = (cb >> 4) + ((((ks >> 4) + quad) ^ li) & 15);
#pragma unroll
                    for (int tn = 0; tn < 2; ++tn) {
                        const v4i bfr = *(const v4i*)&sB[(nh * 32 + tn * 16 + li) * WCROW + gs * 16];
                        acc[0][tn] = __builtin_amdgcn_mfma_i32_16x16x64_i8(af0, bfr, acc[0][tn], 0, 0, 0);
                        acc[1][tn] = __builtin_amdgcn_mfma_i32_16x16x64_i8(af1, bfr, acc[1][tn], 0, 0, 0);
                    }
                }
                // segment flushes: exact fp32 add order c = ((ext+inter)+E)+I
                if (ch == 1) {
#pragma unroll
                    for (int tb = 0; tb < 2; ++tb)
#pragma unroll
                        for (int tn = 0; tn < 2; ++tn) {
#pragma unroll
                            for (int r = 0; r < 4; ++r)
                                c[tb][tn][r] = __fadd_rn(extr[tb][tn][r], (float)acc[tb][tn][r]);
                            acc[tb][tn] = (v4i){0, 0, 0, 0};
                        }
                } else if (ch == 3) {
#pragma unroll
                    for (int tb = 0; tb < 2; ++tb)
#pragma unroll
                        for (int tn = 0; tn < 2; ++tn) {
#pragma unroll
                            for (int r = 0; r < 4; ++r)
                                c[tb][tn][r] = __fadd_rn(c[tb][tn][r], (float)acc[tb][tn][r]);
                            acc[tb][tn] = (v4i){0, 0, 0, 0};
                        }
                }
            }
            // ---- epilogue: I segment, K [1024,1152) = i-plane bits [0,128) ----
            {
                v4i e0 = *(const v4i*)&sAb[r0base + 128];
                v4i e1 = *(const v4i*)&sAb[r1base + 128];
#pragma unroll
                for (int ks = 0; ks < 128; ks += 64) {
                    const int D0 = (ks >> 6) ? 2 : 0;
                    v4i af0 = unpack16((unsigned int)e0[D0], (unsigned int)e0[D0 + 1], qhi, qsh);
                    v4i af1 = unpack16((unsigned int)e1[D0], (unsigned int)e1[D0 + 1], qhi, qsh);
                    const int gs = 64 + ((((ks >> 4) + quad) ^ li) & 7);
#pragma unroll
                    for (int tn = 0; tn < 2; ++tn) {
                        const v4i bfr = *(const v4i*)&sB[(nh * 32 + tn * 16 + li) * WCROW + gs * 16];
                        acc[0][tn] = __builtin_amdgcn_mfma_i32_16x16x64_i8(af0, bfr, acc[0][tn], 0, 0, 0);
                        acc[1][tn] = __builtin_amdgcn_mfma_i32_16x16x64_i8(af1, bfr, acc[1][tn], 0, 0, 0);
                    }
                }
            }
#pragma unroll
            for (int tb = 0; tb < 2; ++tb)
#pragma unroll
                for (int tn = 0; tn < 2; ++tn)
#pragma unroll
                    for (int r = 0; r < 4; ++r)
                        c[tb][tn][r] = __fadd_rn(c[tb][tn][r], (float)acc[tb][tn][r]);
        }

        // LIF update, exact np op order: v' = (v*decay) + c; spike iff v' >= 1.0
        int snow[2][2] = {{0, 0}, {0, 0}};
#pragma unroll
        for (int tb = 0; tb < 2; ++tb)
#pragma unroll
            for (int tn = 0; tn < 2; ++tn)
#pragma unroll
                for (int r = 0; r < 4; ++r) {
                    float vn = __fadd_rn(__fmul_rn(vmem[tb][tn][r], decs[tn]), c[tb][tn][r]);
                    int s = (vn >= 1.0f) ? 1 : 0;
                    vmem[tb][tn][r] = s ? 0.0f : vn;
                    cnt[tb][tn] += s << (r * 8);
                    snow[tb][tn] |= s << r;
                }

        // ballot-packed spike publish into buffer[t] (written once -> no WAR ever)
        if (t < Tt - 1) {
            unsigned char* SW = Sp + (size_t)t * SPTICK;
#pragma unroll
            for (int tb = 0; tb < 2; ++tb)
#pragma unroll
                for (int tn = 0; tn < 2; ++tn)
#pragma unroll
                    for (int r = 0; r < 4; ++r) {
                        unsigned long long mk = __ballot((snow[tb][tn] >> r) & 1);
                        if (li == 0) {   // 4 lanes, one per quad
                            unsigned short v = (unsigned short)(mk >> (unsigned)(quad << 4));
                            int row = bbase + tb * 16 + quad * 4 + r;
                            unsigned char* rb = SW + (size_t)(m * Bb + row) * SPB;
                            if (styp[tn] != 2) {
                                __hip_atomic_store((unsigned short*)(rb + soff[tn]), v,
                                                   __ATOMIC_RELAXED, __HIP_MEMORY_SCOPE_AGENT);
                            } else {
                                // mixed group (n 400..415): E bits li<=8, I bits li>=9
                                __hip_atomic_store((unsigned short*)(rb + 50),
                                                   (unsigned short)(v & 0x01FF),
                                                   __ATOMIC_RELAXED, __HIP_MEMORY_SCOPE_AGENT);
                                __hip_atomic_store((unsigned short*)(rb + 66),
                                                   (unsigned short)(v & 0xFE00),
                                                   __ATOMIC_RELAXED, __HIP_MEMORY_SCOPE_AGENT);
                            }
                        }
                    }
            // completion flag for tick t (covers this tick's spike stores)
            __syncthreads();
            if (tid == 0)
                __hip_atomic_store(&flags[wg * FLAGSTRIDE], t + 1,
                                   __ATOMIC_RELAXED, __HIP_MEMORY_SCOPE_AGENT);
        }
    }

    // out[b][m*N + n] = spike count (single write at the end)
#pragma unroll
    for (int tb = 0; tb < 2; ++tb)
#pragma unroll
        for (int tn = 0; tn < 2; ++tn)
#pragma unroll
            for (int r = 0; r < 4; ++r) {
                int b = bbase + tb * 16 + quad * 4 + r;
                out[(size_t)b * (Mm * Nn) + m * Nn + nels[tn]] =
                    (float)((cnt[tb][tn] >> (r * 8)) & 0xff);
            }
}

extern "C" void kernel_launch(void* const* d_in, const int* in_sizes, int n_in,
                              void* d_out, int out_size, void* d_ws, size_t ws_size,
                              hipStream_t stream) {
    const float* x    = (const float*)d_in[0];
    const float* Win  = (const float*)d_in[1];
    const float* bin  = (const float*)d_in[2];
    const float* Wint = (const float*)d_in[3];
    const float* WEE  = (const float*)d_in[4];
    const float* WEI  = (const float*)d_in[5];
    const float* WIE  = (const float*)d_in[6];
    const float* WII  = (const float*)d_in[7];
    float* out = (float*)d_out;

    char* ws = (char*)d_ws;
    unsigned char* Sp = (unsigned char*)ws;                    // 16 ticks * 393,216 = 6,291,456
    int* flags = (int*)(ws + 16 * SPTICK);                     // 32 KB

    // zero Sp + flags every launch (contiguous span; launch-invariance, r0 lesson)
    hipMemsetAsync(ws, 0, 16 * SPTICK + 32768, stream);
    k_ticks<<<NBLK, 512, 0, stream>>>(Wint, WEE, WEI, WIE, WII,
                                      Sp, x, Win, bin, out, flags);
}

// Round 9
// 196.253 us; speedup vs baseline: 1.4444x; 1.4444x over previous
//
#include <hip/hip_runtime.h>
#include <hip/hip_bf16.h>

#define Mm 8
#define Nn 512
#define NEe 409
#define NIi 103
#define Bb 512
#define Dd 243
#define Tt 16
#define SPB 96         // bit-packed spike row bytes: e-bits[0,64) | i-bits[64,80) | pad[80,96)
#define SPTICK (Mm * Bb * SPB)   // 393,216 B: one spike buffer per tick (16 total -> no WAR)
#define WCROW 1152     // packed weight row bytes (i8): inter(512) | E-rec(512) | I-rec(128, data at [1049,1152))
#define DEC_I 0.33333334f  // (float)(1.0 - 1.0/1.5)
#define NBLK 256
#define FLAGSTRIDE 16  // one flag per 64B cache line
#define SPINMAX 1000000L
#define ABROW 176      // LDS A-bit row stride (mult 16; word-stride 44 -> 2-way-free banks)
#define ZSPAN_U32 1581056  // (16*SPTICK + 32KB flags)/4, contiguous, zeroed every launch

typedef int v4i __attribute__((ext_vector_type(4)));

__device__ __forceinline__ float quantf(float w) {
    // fake_quant forward == clip(round-half-even(w), -8, 7)  (step = 1.0)
    float q = rintf(w);
    return fminf(fmaxf(q, -8.0f), 7.0f);
}

// nibble -> 4 bytes of 0/1: (nib * 0x204081) & 0x01010101 places bit j at byte j.
__device__ __forceinline__ v4i unpack16(unsigned int dl, unsigned int dh, bool qhi, int qsh) {
    unsigned int d = qhi ? dh : dl;
    v4i r;
    r[0] = (int)((((d >> qsh) & 0xFu) * 0x00204081u) & 0x01010101u);
    r[1] = (int)((((d >> (qsh + 4)) & 0xFu) * 0x00204081u) & 0x01010101u);
    r[2] = (int)((((d >> (qsh + 8)) & 0xFu) * 0x00204081u) & 0x01010101u);
    r[3] = (int)((((d >> (qsh + 12)) & 0xFu) * 0x00204081u) & 0x01010101u);
    return r;
}

// ---------------- pack quantized recurrent weights as i8, 4 k's per thread ----------
// K layout: [0,512) inter (prev-mesh e, valid k<409), [512,1024) E-rec (valid jj<409),
// [1024,1152) I-rec REBASED to jj = k-1049 (i-plane bit p=n-384 -> K=1024+p; bits at
// K in [1024,1049) hit zero weights). Also zeroes ALL 16 per-tick spike buffers +
// flags (one contiguous span) every launch: launch-invariance (r0 tripwire lesson).
// NOTE (r8 lesson): keep this a SEPARATE coalesced dispatch. Fusing the pack into
// k_ticks' prologue = 288 scalar divergent loads/thread, 8x duplicated -> +105us.
__global__ void k_pack(const float* __restrict__ Wint, const float* __restrict__ WEE,
                       const float* __restrict__ WEI, const float* __restrict__ WIE,
                       const float* __restrict__ WII, signed char* __restrict__ Wc,
                       unsigned* __restrict__ spz) {
    int gid = blockIdx.x * 256 + threadIdx.x;
#pragma unroll
    for (int z = 0; z < 2; ++z) {
        int i = gid + z * 1179648;
        if (i < ZSPAN_U32) spz[i] = 0u;
    }
    int q = gid;                                     // quad index
    if (q >= (Mm * Nn * WCROW) / 4) return;
    int k0 = (q * 4) % WCROW;
    int n  = ((q * 4) / WCROW) & (Nn - 1);
    int m  = (q * 4) / (WCROW * Nn);
    char out4[4];
#pragma unroll
    for (int j = 0; j < 4; ++j) {
        int k = k0 + j;
        float w = 0.0f;
        if (k < 512) {
            if (k < NEe) w = Wint[((((m + 7) & 7) * Nn) + n) * NEe + k];
        } else if (k < 1024) {
            int jj = k - 512;
            if (jj < NEe) w = (n < NEe) ? WEE[((m * NEe) + n) * NEe + jj]
                                        : WEI[((m * NIi) + (n - NEe)) * NEe + jj];
        } else {
            int jj = k - 1049;                       // rebased I segment
            if (jj >= 0 && jj < NIi) w = (n < NEe) ? WIE[((m * NEe) + n) * NIi + jj]
                                        : WII[((m * NIi) + (n - NEe)) * NIi + jj];
        }
        out4[j] = (signed char)(int)quantf(w);
    }
    *(int*)&Wc[q * 4] = *(int*)out4;
}

// ---------------- persistent 16-tick LIF + fused ext-GEMM prologue ------------------
// 256 blocks x 512 thr, tile 64b x 128n. Best-verified structure (r4, 198.7us):
// (1) ext_proj computed IN-KERNEL: each block runs the r8-verified chunk-64 GEMM for
//     its two 64x64 sub-tiles (2 thread-groups of 256, exact same fp32 op order),
//     redistributes through a 32KB LDS buffer (bitwise-exact data movement).
// (2) 16 per-tick spike buffers (all zeroed each launch) -> WAR gone: flag wait-set
//     is RAW-only {pm,m} x 4nt' (8 flags); block-wide wait + block-wide staging
//     (r3/r7 lesson: per-word tag-polls and per-wave staging both regress — the
//     block-wide protocol keeps all 8 flag loads + 1152 stage loads in flight).
// Weights resident in LDS (144 KB, granule XOR-swizzle); spikes bit-packed
// (96 B/row); ballot-packed publish. LDS 155 KB, 1 block/CU.
__global__ void __launch_bounds__(512, 2)
k_ticks(const signed char* __restrict__ Wc,
        unsigned char* __restrict__ Sp,
        const float* __restrict__ x,
        const float* __restrict__ Win,
        const float* __restrict__ bin,
        float* __restrict__ out,
        int* __restrict__ flags) {
    __shared__ __align__(16) signed char sB[128 * WCROW];     // 144 KB resident weights
    __shared__ __align__(16) unsigned char sAb[64 * ABROW];   // 11 KB per-tick spike bits

    const int wg = blockIdx.x;           // 256: m(8) x bt(8) x nt(4)
    const int m  = wg & 7;               // mesh -> XCD affinity heuristic
    const int bt = (wg >> 3) & 7;
    const int nt = wg >> 6;              // 0..3
    const int b0 = bt * 64;
    const int n0 = nt * 128;
    const int pm = (m + 7) & 7;

    const int tid  = threadIdx.x;        // 0..511
    const int w    = tid >> 6;           // 0..7
    const int lane = tid & 63;
    const int bh   = w & 1;              // 32-row half of b-tile
    const int nh   = w >> 1;             // 0..3: 32-col slice of n-tile
    const int quad = lane >> 4;
    const int li   = lane & 15;

    // RAW wait-set for tid<8: mesh {pm,m}[tid>=4], nt'=tid&3, same bt
    int waitIdx = 0;
    if (tid < 8) {
        int mm = (tid < 4) ? pm : m;
        waitIdx = (((tid & 3) << 6) | (bt << 3) | mm) * FLAGSTRIDE;
    }

    float decs[2]; int nels[2];
    int styp[2], soff[2];                // publish: 0/1 = plain halfword @soff, 2 = mixed
#pragma unroll
    for (int tn = 0; tn < 2; ++tn) {
        int n = n0 + nh * 32 + tn * 16 + li;
        nels[tn] = n;
        decs[tn] = (n < NEe) ? 0.5f : DEC_I;
        int nb = n0 + nh * 32 + tn * 16;           // wave-uniform 16-group base
        if (nb < 400)      { styp[tn] = 0; soff[tn] = nb >> 3; }
        else if (nb == 400){ styp[tn] = 2; soff[tn] = 50; }
        else               { styp[tn] = 1; soff[tn] = 64 + ((nb - 384) >> 3); }
    }
    const int bbase = b0 + bh * 32;

    // ---- fused ext phase: two 64x64 sub-tiles, r8-verified chunk-64 logic verbatim --
    // group g = tid>>8 handles n columns [n0+g*64, +64); LDS xs/wsm aliased inside sB.
    {
        const int g   = tid >> 8;
        const int t8  = tid & 255;
        const int n0e = n0 + g * 64;
        float* xs  = (float*)sB + g * (2 * 64 * 68);
        float* wsm = xs + 64 * 68;
        const int etb4 = (t8 & 15) * 4;
        const int etn4 = (t8 >> 4) * 4;
        const int sr = t8 >> 2;
        const int sc = (t8 & 3) * 16;
        float c[4][4];
#pragma unroll
        for (int i = 0; i < 4; ++i)
#pragma unroll
            for (int j = 0; j < 4; ++j) c[i][j] = 0.0f;

        for (int d0 = 0; d0 < Dd; d0 += 64) {
#pragma unroll
            for (int j = 0; j < 16; ++j) {
                int d = d0 + sc + j;
                float xv = 0.0f, wv = 0.0f;
                if (d < Dd) {
                    xv = x[(b0 + sr) * Dd + d];
                    wv = quantf(Win[((m * Nn) + n0e + sr) * Dd + d]);
                }
                xs[(sc + j) * 68 + sr] = xv;
                wsm[(sc + j) * 68 + sr] = wv;
            }
            __syncthreads();
            const int dmax = min(64, Dd - d0);
            for (int d = 0; d < dmax; ++d) {
                float4 av = *(const float4*)&xs[d * 68 + etb4];
                float4 wv = *(const float4*)&wsm[d * 68 + etn4];
                float a[4] = {av.x, av.y, av.z, av.w};
                float wq[4] = {wv.x, wv.y, wv.z, wv.w};
#pragma unroll
                for (int i = 0; i < 4; ++i)
#pragma unroll
                    for (int j = 0; j < 4; ++j)
                        c[i][j] = fmaf(a[i], wq[j], c[i][j]);
            }
            __syncthreads();
        }
        // redistribute: extbuf[64][128] fp32 (32KB) aliases start of sB (safe: all
        // xs/wsm reads drained by the loop-final barrier)
        float* extbuf = (float*)sB;
#pragma unroll
        for (int i = 0; i < 4; ++i)
#pragma unroll
            for (int j = 0; j < 4; ++j)
                extbuf[(etb4 + i) * 128 + g * 64 + etn4 + j] =
                    __fadd_rn(c[i][j], bin[m * Nn + n0e + etn4 + j]);
        __syncthreads();
    }

    // per-thread persistent ext values for all 16 ticks (bitwise = k_ext output)
    float extr[2][2][4];
#pragma unroll
    for (int tb = 0; tb < 2; ++tb)
#pragma unroll
        for (int tn = 0; tn < 2; ++tn)
#pragma unroll
            for (int r = 0; r < 4; ++r)
                extr[tb][tn][r] = ((const float*)sB)[(bh * 32 + tb * 16 + quad * 4 + r) * 128
                                                     + (nels[tn] - n0)];
    __syncthreads();   // all extr reads drained before B preload overwrites sB

    // ---- one-time B preload: 9216 16B granules, XOR-swizzled within 256B spans ----
    const signed char* WcBase = Wc + (size_t)(m * Nn + n0) * WCROW;
#pragma unroll
    for (int j = 0; j < 18; ++j) {
        int task = tid + j * 512;                 // exactly 9216 = 512*18
        int row = task / 72, gg = task % 72;
        v4i v = *(const v4i*)(WcBase + (size_t)row * WCROW + gg * 16);
        int gs = (gg < 64) ? ((gg & 48) | ((gg ^ row) & 15))
                           : (64 + ((gg ^ row) & 7));
        *(v4i*)&sB[row * WCROW + gs * 16] = v;
    }
    // never-written sAb slots (e-bits [416,512) both halves) zeroed once:
    // slots 13,14,15 (prev-e) and 29,30,31 (own-e) per row.
    if (tid < 384) {
        int row = tid / 6, z = tid - (tid / 6) * 6;
        int s = (z < 3) ? (13 + z) : (26 + z);     // 13,14,15 / 29,30,31
        *(unsigned*)&sAb[row * ABROW + s * 4] = 0u;
    }
    __syncthreads();

    float vmem[2][2][4];
    int cnt[2][2];
#pragma unroll
    for (int tb = 0; tb < 2; ++tb)
#pragma unroll
        for (int tn = 0; tn < 2; ++tn) {
            cnt[tb][tn] = 0;
#pragma unroll
            for (int r = 0; r < 4; ++r) vmem[tb][tn][r] = 0.0f;
        }

    const bool qhi = (quad >= 2);
    const int qsh = (quad & 1) << 4;
    const int r0base = (bh * 32 + li) * ABROW;
    const int r1base = (bh * 32 + 16 + li) * ABROW;

    for (int t = 0; t < Tt; ++t) {
        float c[2][2][4];

        if (t == 0) {
            // spikes all zero: c = ((ext + 0) + 0) + 0, exact fadd chain as GEMM path
#pragma unroll
            for (int tb = 0; tb < 2; ++tb)
#pragma unroll
                for (int tn = 0; tn < 2; ++tn)
#pragma unroll
                    for (int r = 0; r < 4; ++r)
                        c[tb][tn][r] = __fadd_rn(__fadd_rn(__fadd_rn(extr[tb][tn][r], 0.0f), 0.0f), 0.0f);
        } else {
            // RAW wait: 8 flags {pm,m} x nt' at level t, then bulk-stage with full MLP
            if (tid < 8) {
                long spin = 0;
                while (__hip_atomic_load(&flags[waitIdx],
                                         __ATOMIC_RELAXED, __HIP_MEMORY_SCOPE_AGENT) < t) {
                    __builtin_amdgcn_s_sleep(2);
                    if (++spin > SPINMAX) break;   // bail: wrong answer beats a hang
                }
            }
            __syncthreads();

            // ---- stage A-bits: LDS row = [prev-e 64B | own-e 64B | own-i 16B | pad] ----
            const unsigned char* SR = Sp + (size_t)(t - 1) * SPTICK;
            const unsigned char* PrevRow = SR + (size_t)(pm * Bb + b0) * SPB;
            const unsigned char* OwnRow  = SR + (size_t)(m  * Bb + b0) * SPB;
#pragma unroll
            for (int j = 0; j < 3; ++j) {
                int task = tid + j * 512;              // 1152 u64 tasks
                if (task < 1152) {
                    int row = task / 18, s = task % 18;
                    const unsigned char* src;
                    int dstoff;
                    if (s < 8)       { src = PrevRow + (size_t)row * SPB + s * 8;            dstoff = s * 8; }
                    else if (s < 16) { src = OwnRow  + (size_t)row * SPB + (s - 8) * 8;      dstoff = s * 8; }
                    else             { src = OwnRow  + (size_t)row * SPB + 64 + (s - 16) * 8; dstoff = 128 + (s - 16) * 8; }
                    unsigned long long vb = __hip_atomic_load((const unsigned long long*)src,
                                               __ATOMIC_RELAXED, __HIP_MEMORY_SCOPE_AGENT);
                    *(unsigned long long*)&sAb[row * ABROW + dstoff] = vb;
                }
            }
            __syncthreads();

            v4i acc[2][2];
#pragma unroll
            for (int tb = 0; tb < 2; ++tb)
#pragma unroll
                for (int tn = 0; tn < 2; ++tn) acc[tb][tn] = (v4i){0, 0, 0, 0};

            // ---- 4 full 256-wide K-chunks, no barriers (B resident, A in regs) ----
#pragma unroll
            for (int ch = 0; ch < 4; ++ch) {
                const int cb = ch << 8;
                v4i a0lo = *(const v4i*)&sAb[r0base + (cb >> 3)];
                v4i a0hi = *(const v4i*)&sAb[r0base + (cb >> 3) + 16];
                v4i a1lo = *(const v4i*)&sAb[r1base + (cb >> 3)];
                v4i a1hi = *(const v4i*)&sAb[r1base + (cb >> 3) + 16];
#pragma unroll
                for (int ks = 0; ks < 256; ks += 64) {
                    v4i s0 = (ks < 128) ? a0lo : a0hi;
                    v4i s1 = (ks < 128) ? a1lo : a1hi;
                    const int D0 = ((ks >> 6) & 1) ? 2 : 0;
                    v4i af0 = unpack16((unsigned int)s0[D0], (unsigned int)s0[D0 + 1], qhi, qsh);
                    v4i af1 = unpack16((unsigned int)s1[D0], (unsigned int)s1[D0 + 1], qhi, qsh);
                    const int gs = (cb >> 4) + ((((ks >> 4) + quad) ^ li) & 15);
#pragma unroll
                    for (int tn = 0; tn < 2; ++tn) {
                        const v4i bfr = *(const v4i*)&sB[(nh * 32 + tn * 16 + li) * WCROW + gs * 16];
                        acc[0][tn] = __builtin_amdgcn_mfma_i32_16x16x64_i8(af0, bfr, acc[0][tn], 0, 0, 0);
                        acc[1][tn] = __builtin_amdgcn_mfma_i32_16x16x64_i8(af1, bfr, acc[1][tn], 0, 0, 0);
                    }
                }
                // segment flushes: exact fp32 add order c = ((ext+inter)+E)+I
                if (ch == 1) {
#pragma unroll
                    for (int tb = 0; tb < 2; ++tb)
#pragma unroll
                        for (int tn = 0; tn < 2; ++tn) {
#pragma unroll
                            for (int r = 0; r < 4; ++r)
                                c[tb][tn][r] = __fadd_rn(extr[tb][tn][r], (float)acc[tb][tn][r]);
                            acc[tb][tn] = (v4i){0, 0, 0, 0};
                        }
                } else if (ch == 3) {
#pragma unroll
                    for (int tb = 0; tb < 2; ++tb)
#pragma unroll
                        for (int tn = 0; tn < 2; ++tn) {
#pragma unroll
                            for (int r = 0; r < 4; ++r)
                                c[tb][tn][r] = __fadd_rn(c[tb][tn][r], (float)acc[tb][tn][r]);
                            acc[tb][tn] = (v4i){0, 0, 0, 0};
                        }
                }
            }
            // ---- epilogue: I segment, K [1024,1152) = i-plane bits [0,128) ----
            {
                v4i e0 = *(const v4i*)&sAb[r0base + 128];
                v4i e1 = *(const v4i*)&sAb[r1base + 128];
#pragma unroll
                for (int ks = 0; ks < 128; ks += 64) {
                    const int D0 = (ks >> 6) ? 2 : 0;
                    v4i af0 = unpack16((unsigned int)e0[D0], (unsigned int)e0[D0 + 1], qhi, qsh);
                    v4i af1 = unpack16((unsigned int)e1[D0], (unsigned int)e1[D0 + 1], qhi, qsh);
                    const int gs = 64 + ((((ks >> 4) + quad) ^ li) & 7);
#pragma unroll
                    for (int tn = 0; tn < 2; ++tn) {
                        const v4i bfr = *(const v4i*)&sB[(nh * 32 + tn * 16 + li) * WCROW + gs * 16];
                        acc[0][tn] = __builtin_amdgcn_mfma_i32_16x16x64_i8(af0, bfr, acc[0][tn], 0, 0, 0);
                        acc[1][tn] = __builtin_amdgcn_mfma_i32_16x16x64_i8(af1, bfr, acc[1][tn], 0, 0, 0);
                    }
                }
            }
#pragma unroll
            for (int tb = 0; tb < 2; ++tb)
#pragma unroll
                for (int tn = 0; tn < 2; ++tn)
#pragma unroll
                    for (int r = 0; r < 4; ++r)
                        c[tb][tn][r] = __fadd_rn(c[tb][tn][r], (float)acc[tb][tn][r]);
        }

        // LIF update, exact np op order: v' = (v*decay) + c; spike iff v' >= 1.0
        int snow[2][2] = {{0, 0}, {0, 0}};
#pragma unroll
        for (int tb = 0; tb < 2; ++tb)
#pragma unroll
            for (int tn = 0; tn < 2; ++tn)
#pragma unroll
                for (int r = 0; r < 4; ++r) {
                    float vn = __fadd_rn(__fmul_rn(vmem[tb][tn][r], decs[tn]), c[tb][tn][r]);
                    int s = (vn >= 1.0f) ? 1 : 0;
                    vmem[tb][tn][r] = s ? 0.0f : vn;
                    cnt[tb][tn] += s << (r * 8);
                    snow[tb][tn] |= s << r;
                }

        // ballot-packed spike publish into buffer[t] (written once -> no WAR ever)
        if (t < Tt - 1) {
            unsigned char* SW = Sp + (size_t)t * SPTICK;
#pragma unroll
            for (int tb = 0; tb < 2; ++tb)
#pragma unroll
                for (int tn = 0; tn < 2; ++tn)
#pragma unroll
                    for (int r = 0; r < 4; ++r) {
                        unsigned long long mk = __ballot((snow[tb][tn] >> r) & 1);
                        if (li == 0) {   // 4 lanes, one per quad
                            unsigned short v = (unsigned short)(mk >> (unsigned)(quad << 4));
                            int row = bbase + tb * 16 + quad * 4 + r;
                            unsigned char* rb = SW + (size_t)(m * Bb + row) * SPB;
                            if (styp[tn] != 2) {
                                __hip_atomic_store((unsigned short*)(rb + soff[tn]), v,
                                                   __ATOMIC_RELAXED, __HIP_MEMORY_SCOPE_AGENT);
                            } else {
                                // mixed group (n 400..415): E bits li<=8, I bits li>=9
                                __hip_atomic_store((unsigned short*)(rb + 50),
                                                   (unsigned short)(v & 0x01FF),
                                                   __ATOMIC_RELAXED, __HIP_MEMORY_SCOPE_AGENT);
                                __hip_atomic_store((unsigned short*)(rb + 66),
                                                   (unsigned short)(v & 0xFE00),
                                                   __ATOMIC_RELAXED, __HIP_MEMORY_SCOPE_AGENT);
                            }
                        }
                    }
            // completion flag for tick t (covers this tick's spike stores)
            __syncthreads();
            if (tid == 0)
                __hip_atomic_store(&flags[wg * FLAGSTRIDE], t + 1,
                                   __ATOMIC_RELAXED, __HIP_MEMORY_SCOPE_AGENT);
        }
    }

    // out[b][m*N + n] = spike count (single write at the end)
#pragma unroll
    for (int tb = 0; tb < 2; ++tb)
#pragma unroll
        for (int tn = 0; tn < 2; ++tn)
#pragma unroll
            for (int r = 0; r < 4; ++r) {
                int b = bbase + tb * 16 + quad * 4 + r;
                out[(size_t)b * (Mm * Nn) + m * Nn + nels[tn]] =
                    (float)((cnt[tb][tn] >> (r * 8)) & 0xff);
            }
}

extern "C" void kernel_launch(void* const* d_in, const int* in_sizes, int n_in,
                              void* d_out, int out_size, void* d_ws, size_t ws_size,
                              hipStream_t stream) {
    const float* x    = (const float*)d_in[0];
    const float* Win  = (const float*)d_in[1];
    const float* bin  = (const float*)d_in[2];
    const float* Wint = (const float*)d_in[3];
    const float* WEE  = (const float*)d_in[4];
    const float* WEI  = (const float*)d_in[5];
    const float* WIE  = (const float*)d_in[6];
    const float* WII  = (const float*)d_in[7];
    float* out = (float*)d_out;

    char* ws = (char*)d_ws;
    signed char* Wc   = (signed char*)ws;                      // 8*512*1152 = 4,718,592
    unsigned char* Sp = (unsigned char*)(ws + 4718592);        // 16 ticks * 393,216 = 6,291,456
    int* flags = (int*)(ws + 4718592 + 16 * SPTICK);           // 32 KB (zeroed with Sp in k_pack)

    k_pack<<<(Mm * Nn * WCROW / 4 + 255) / 256, 256, 0, stream>>>(Wint, WEE, WEI, WIE, WII, Wc,
                                                                  (unsigned*)Sp);
    k_ticks<<<NBLK, 512, 0, stream>>>(Wc, Sp, x, Win, bin, out, flags);
}